// Round 1
// baseline (43550.003 us; speedup 1.0000x reference)
//
#include <hip/hip_runtime.h>
#include <math.h>

// GRU encoder: B=64, T=1024, V=32000, E=256, U=1024, gates [z,r,h], reset_after.
// Round 0: correctness-first f32 baseline.
//   - 1024 per-step kernel launches (graph-captured).
//   - W_rec/W_in transposed into ws once per call (runtime ws_size check with
//     strided-load fallback) so the K-loop does wave-uniform float4 weight loads.
//   - h staged per 128-k chunk into LDS [b][k] stride-129 (2-way read = free).
//   - thread = (b lane, u, k-half): 2 waves/SIMD, cross-half LDS reduction.

#define B_  64
#define T_  1024
#define U_  1024
#define E_  256
#define U3_ 3072

__global__ __launch_bounds__(256) void transpose_f32(
    const float* __restrict__ in, float* __restrict__ out, int R, int C)
{
    __shared__ float tile[32][33];
    const int bc = blockIdx.x * 32;
    const int br = blockIdx.y * 32;
    const int tx = threadIdx.x & 31;
    const int ty = threadIdx.x >> 5;   // 0..7
#pragma unroll
    for (int i = 0; i < 32; i += 8)
        tile[ty + i][tx] = in[(size_t)(br + ty + i) * C + (bc + tx)];
    __syncthreads();
#pragma unroll
    for (int i = 0; i < 32; i += 8)
        out[(size_t)(bc + ty + i) * R + (br + tx)] = tile[tx][ty + i];
}

template<bool USE_WT>
__global__ __launch_bounds__(512) void gru_step(
    const float* __restrict__ h_src, int h_stride,   // h_{t-1}: rows b, stride in floats
    const int*   __restrict__ x, int t,
    const float* __restrict__ emb,                   // [V][E]
    const float* __restrict__ Wrec,                  // [U][3U]   (fallback path)
    const float* __restrict__ WrecT,                 // [3U][U]   (transposed)
    const float* __restrict__ Win,                   // [E][3U]
    const float* __restrict__ WinT,                  // [3U][E]
    const float* __restrict__ b_in,
    const float* __restrict__ b_rec,
    float* __restrict__ out)                         // [B][T][U] ++ [B][U]
{
    __shared__ float sh[64 * 129];                   // [b][k-chunk], stride 129
    const int tid = (int)threadIdx.x;
    const int b   = tid & 63;
    const int j   = tid >> 6;        // 0..7
    const int uj  = j & 3;
    const int kh  = j >> 2;          // k-half within each 128-chunk
    const int u   = blockIdx.x * 4 + uj;

    float az = 0.f, ar = 0.f, arh = 0.f, axh = 0.f;

    // ---------- recurrent projection: K = U_ over h_{t-1} ----------
    for (int kc = 0; kc < U_; kc += 128) {
#pragma unroll
        for (int l = tid; l < 2048; l += 512) {
            const int row = l >> 5, c4 = l & 31;
            const int c4r = (c4 + row) & 31;         // rotate: LDS write conflicts -> 4-way
            const float4 v = *reinterpret_cast<const float4*>(
                h_src + (size_t)row * h_stride + (kc + c4r * 4));
            float* d = &sh[row * 129 + c4r * 4];
            d[0] = v.x; d[1] = v.y; d[2] = v.z; d[3] = v.w;
        }
        __syncthreads();
        const float* hrow = &sh[b * 129 + kh * 64];
        const int kb = kc + kh * 64;
        if (USE_WT) {
            const float4* wz = reinterpret_cast<const float4*>(WrecT + (size_t)u * U_ + kb);
            const float4* wr = reinterpret_cast<const float4*>(WrecT + (size_t)(U_ + u) * U_ + kb);
            const float4* wh = reinterpret_cast<const float4*>(WrecT + (size_t)(2 * U_ + u) * U_ + kb);
#pragma unroll 8
            for (int k4 = 0; k4 < 16; ++k4) {
                const float4 z4 = wz[k4], r4 = wr[k4], h4 = wh[k4];
                const float h0 = hrow[k4 * 4 + 0], h1 = hrow[k4 * 4 + 1];
                const float h2 = hrow[k4 * 4 + 2], h3 = hrow[k4 * 4 + 3];
                az  += h0 * z4.x; az  += h1 * z4.y; az  += h2 * z4.z; az  += h3 * z4.w;
                ar  += h0 * r4.x; ar  += h1 * r4.y; ar  += h2 * r4.z; ar  += h3 * r4.w;
                arh += h0 * h4.x; arh += h1 * h4.y; arh += h2 * h4.z; arh += h3 * h4.w;
            }
        } else {
#pragma unroll 4
            for (int k = 0; k < 64; ++k) {
                const float hv = hrow[k];
                const size_t roff = (size_t)(kb + k) * U3_;
                az  += hv * Wrec[roff + u];
                ar  += hv * Wrec[roff + U_ + u];
                arh += hv * Wrec[roff + 2 * U_ + u];
            }
        }
        __syncthreads();
    }

    // ---------- input projection: K = E_ over emb[x[:,t]] ----------
    for (int kc = 0; kc < E_; kc += 128) {
#pragma unroll
        for (int l = tid; l < 2048; l += 512) {
            const int row = l >> 5, c4 = l & 31;
            const int c4r = (c4 + row) & 31;
            const int tok = x[row * T_ + t];
            const float4 v = *reinterpret_cast<const float4*>(
                emb + (size_t)tok * E_ + (kc + c4r * 4));
            float* d = &sh[row * 129 + c4r * 4];
            d[0] = v.x; d[1] = v.y; d[2] = v.z; d[3] = v.w;
        }
        __syncthreads();
        const float* erow = &sh[b * 129 + kh * 64];
        const int kb = kc + kh * 64;
        if (USE_WT) {
            const float4* wz = reinterpret_cast<const float4*>(WinT + (size_t)u * E_ + kb);
            const float4* wr = reinterpret_cast<const float4*>(WinT + (size_t)(U_ + u) * E_ + kb);
            const float4* wh = reinterpret_cast<const float4*>(WinT + (size_t)(2 * U_ + u) * E_ + kb);
#pragma unroll 8
            for (int k4 = 0; k4 < 16; ++k4) {
                const float4 z4 = wz[k4], r4 = wr[k4], h4 = wh[k4];
                const float h0 = erow[k4 * 4 + 0], h1 = erow[k4 * 4 + 1];
                const float h2 = erow[k4 * 4 + 2], h3 = erow[k4 * 4 + 3];
                az  += h0 * z4.x; az  += h1 * z4.y; az  += h2 * z4.z; az  += h3 * z4.w;
                ar  += h0 * r4.x; ar  += h1 * r4.y; ar  += h2 * r4.z; ar  += h3 * r4.w;
                axh += h0 * h4.x; axh += h1 * h4.y; axh += h2 * h4.z; axh += h3 * h4.w;
            }
        } else {
#pragma unroll 4
            for (int k = 0; k < 64; ++k) {
                const float ev = erow[k];
                const size_t roff = (size_t)(kb + k) * U3_;
                az  += ev * Win[roff + u];
                ar  += ev * Win[roff + U_ + u];
                axh += ev * Win[roff + 2 * U_ + u];
            }
        }
        __syncthreads();
    }

    // ---------- cross-half reduction + gates ----------
    if (kh == 1) {
        sh[(0 * 4 + uj) * 64 + b] = az;
        sh[(1 * 4 + uj) * 64 + b] = ar;
        sh[(2 * 4 + uj) * 64 + b] = arh;
        sh[(3 * 4 + uj) * 64 + b] = axh;
    }
    __syncthreads();
    if (kh == 0) {
        az  += sh[(0 * 4 + uj) * 64 + b];
        ar  += sh[(1 * 4 + uj) * 64 + b];
        arh += sh[(2 * 4 + uj) * 64 + b];
        axh += sh[(3 * 4 + uj) * 64 + b];

        const float bz  = b_in[u]          + b_rec[u];
        const float brr = b_in[U_ + u]     + b_rec[U_ + u];
        const float bxh = b_in[2 * U_ + u];
        const float brh = b_rec[2 * U_ + u];

        const float z  = 1.f / (1.f + expf(-(az + bz)));
        const float r  = 1.f / (1.f + expf(-(ar + brr)));
        const float hh = tanhf(axh + bxh + r * (arh + brh));
        const float hp = h_src[(size_t)b * h_stride + u];
        const float hn = z * hp + (1.f - z) * hh;

        out[(size_t)b * ((size_t)T_ * U_) + (size_t)t * U_ + u] = hn;
        if (t == T_ - 1)
            out[(size_t)B_ * T_ * U_ + (size_t)b * U_ + u] = hn;
    }
}

extern "C" void kernel_launch(void* const* d_in, const int* in_sizes, int n_in,
                              void* d_out, int out_size, void* d_ws, size_t ws_size,
                              hipStream_t stream) {
    (void)in_sizes; (void)n_in; (void)out_size;
    const int*   x     = (const int*)  d_in[0];
    const float* init  = (const float*)d_in[1];
    const float* emb   = (const float*)d_in[2];
    const float* Win   = (const float*)d_in[3];
    const float* Wrec  = (const float*)d_in[4];
    const float* b_in  = (const float*)d_in[5];
    const float* b_rec = (const float*)d_in[6];
    float* out = (float*)d_out;

    float* WrecT = (float*)d_ws;                       // [3072][1024]
    float* WinT  = WrecT + (size_t)U3_ * U_;           // [3072][256]
    const size_t need = ((size_t)U3_ * U_ + (size_t)U3_ * E_) * sizeof(float);
    const bool useWT = (d_ws != nullptr) && (ws_size >= need);

    if (useWT) {
        transpose_f32<<<dim3(U3_ / 32, U_ / 32), 256, 0, stream>>>(Wrec, WrecT, U_, U3_);
        transpose_f32<<<dim3(U3_ / 32, E_ / 32), 256, 0, stream>>>(Win,  WinT,  E_, U3_);
        for (int t = 0; t < T_; ++t) {
            const float* hsrc = (t == 0) ? init : (out + (size_t)(t - 1) * U_);
            const int hs = (t == 0) ? U_ : T_ * U_;
            gru_step<true><<<256, 512, 0, stream>>>(hsrc, hs, x, t, emb,
                Wrec, WrecT, Win, WinT, b_in, b_rec, out);
        }
    } else {
        for (int t = 0; t < T_; ++t) {
            const float* hsrc = (t == 0) ? init : (out + (size_t)(t - 1) * U_);
            const int hs = (t == 0) ? U_ : T_ * U_;
            gru_step<false><<<256, 512, 0, stream>>>(hsrc, hs, x, t, emb,
                Wrec, WrecT, Win, WinT, b_in, b_rec, out);
        }
    }
}

// Round 2
// 16176.781 us; speedup vs baseline: 2.6921x; 2.6921x over previous
//
#include <hip/hip_runtime.h>
#include <hip/hip_bf16.h>
#include <math.h>

// GRU encoder: B=64, T=1024, V=32000, E=256, U=1024, gates [z,r,h], reset_after.
// Round 2: split-bf16 (hi+lo) MFMA recurrence, 3-term (AhBh + AhBl + AlBh).
//   - All operands pre-packed into MFMA fragment-major layouts in ws:
//     * WrecF/WinF: built once per call from f32 weights, columns permuted so a
//       64-col block = [z|r|h] x 16 u -> gate math is per-lane (lane&15 = u).
//     * eF: input-projection A-fragments for ALL t (gather+split once per call).
//     * hF: h hi/lo fragments, parity double-buffered, written by the epilogue.
//   - Step kernel: 128 blocks (64 col-blocks x 2 m-splits) x 128 thr (2 k-waves).
//     K-loop = coalesced dwordx4 frag loads + MFMAs only; no LDS, no barriers.
//   - Fallback to f32 path (Round 0) if ws_size too small.

#define B_  64
#define T_  1024
#define U_  1024
#define E_  256
#define U3_ 3072

typedef __attribute__((ext_vector_type(8))) short short8;
typedef __attribute__((ext_vector_type(4))) float f32x4;

// ---- fragment offsets (in ushort units) ----
__device__ __forceinline__ size_t wrecOff(int cb,int nt,int ch,int sp){ return ((((size_t)cb*3+nt)*32+ch)*2+sp)*512; }
__device__ __forceinline__ size_t winOff (int cb,int nt,int ch,int sp){ return ((((size_t)cb*3+nt)*8 +ch)*2+sp)*512; }
__device__ __forceinline__ size_t hOff   (int mt,int ch,int sp){ return (((size_t)mt*32+ch)*2+sp)*512; }
__device__ __forceinline__ size_t eOff   (int mt,int ch,int sp){ return (((size_t)mt*8 +ch)*2+sp)*512; }

__device__ __forceinline__ void split_bf16(float v, unsigned short& hi, unsigned short& lo){
  union {float f; unsigned u;} a; a.f = v;
  unsigned r = a.u + 0x7FFFu + ((a.u>>16)&1u);
  hi = (unsigned short)(r>>16);
  union {unsigned u; float f;} hf; hf.u = ((unsigned)hi)<<16;
  float rem = v - hf.f;
  union {float f; unsigned u;} b; b.f = rem;
  unsigned r2 = b.u + 0x7FFFu + ((b.u>>16)&1u);
  lo = (unsigned short)(r2>>16);
}

// ---- once-per-call fragment builders ----
__global__ __launch_bounds__(256) void build_wfrag(
    const float* __restrict__ W, unsigned short* __restrict__ dst, int nch)
{
  const int blk = blockIdx.x;              // grid = 64*3*nch
  const int ch = blk % nch;
  const int nt = (blk/nch) % 3;
  const int cb = blk/(nch*3);
  const size_t base = ((((size_t)cb*3+nt)*nch+ch)*2)*512;
  for (int e = threadIdx.x; e < 512; e += 256){
    const int ln = e>>3, j = e&7;
    const int k = ch*32 + (ln>>4)*8 + j;
    const int c = nt*1024 + cb*16 + (ln&15);
    unsigned short hi, lo; split_bf16(W[(size_t)k*U3_ + c], hi, lo);
    dst[base + e]       = hi;
    dst[base + 512 + e] = lo;
  }
}

__global__ __launch_bounds__(256) void build_efrag(
    const int* __restrict__ x, const float* __restrict__ emb,
    unsigned short* __restrict__ eF)
{
  const int t = blockIdx.x;                // grid = 1024
  const size_t tbase = (size_t)t * 32768;
  for (int e = threadIdx.x; e < 16384; e += 256){
    const int mt = e >> 12; const int r = e & 4095;
    const int ch = r >> 9;  const int r2 = r & 511;
    const int ln = r2>>3, j = r2&7;
    const int b = mt*16 + (ln&15);
    const int k = ch*32 + (ln>>4)*8 + j;
    const int tok = x[b*T_ + t];
    unsigned short hi, lo; split_bf16(emb[(size_t)tok*E_ + k], hi, lo);
    const size_t off = tbase + (((size_t)mt*8+ch)*2)*512 + r2;
    eF[off]       = hi;
    eF[off + 512] = lo;
  }
}

__global__ __launch_bounds__(256) void build_hfrag(
    const float* __restrict__ h0, unsigned short* __restrict__ hF)
{
  for (int e = blockIdx.x*blockDim.x + threadIdx.x; e < 65536; e += gridDim.x*blockDim.x){
    const int mt = e >> 14; const int r = e & 16383;
    const int ch = r >> 9;  const int r2 = r & 511;
    const int ln = r2>>3, j = r2&7;
    const int b = mt*16 + (ln&15);
    const int k = ch*32 + (ln>>4)*8 + j;
    unsigned short hi, lo; split_bf16(h0[(size_t)b*U_ + k], hi, lo);
    const size_t off = (((size_t)mt*32+ch)*2)*512 + r2;
    hF[off]       = hi;
    hF[off + 512] = lo;
  }
}

// ---- per-step MFMA kernel ----
__global__ __launch_bounds__(128) void gru_step_mfma(
    const unsigned short* __restrict__ hFsrc, unsigned short* __restrict__ hFdst,
    const unsigned short* __restrict__ eFt,
    const unsigned short* __restrict__ WrecF, const unsigned short* __restrict__ WinF,
    const float* __restrict__ hprev, long long hstride,
    const float* __restrict__ b_in, const float* __restrict__ b_rec,
    float* __restrict__ out, int t)
{
  const int ln = threadIdx.x & 63;
  const int kw = threadIdx.x >> 6;         // k-split wave 0/1
  const int cb = blockIdx.x & 63;          // column block (16 u, 3 gates)
  const int mw = blockIdx.x >> 6;          // m-split 0/1 (32 b-rows)

  f32x4 accR[2][3], accI[2][3];
  #pragma unroll
  for (int m=0;m<2;m++)
    #pragma unroll
    for (int nt=0;nt<3;nt++){
      accR[m][nt] = (f32x4){0.f,0.f,0.f,0.f};
      accI[m][nt] = (f32x4){0.f,0.f,0.f,0.f};
    }

  // ---- recurrent projection: 16 chunks of K=32 per k-wave ----
  {
    const int ch0 = kw*16;
    #pragma unroll 2
    for (int ci=0; ci<16; ci++){
      const int ch = ch0 + ci;
      short8 ah[2], al[2], bh[3], bl[3];
      #pragma unroll
      for (int m=0;m<2;m++){
        const int mt = mw*2+m;
        ah[m] = *(const short8*)(hFsrc + hOff(mt,ch,0) + ln*8);
        al[m] = *(const short8*)(hFsrc + hOff(mt,ch,1) + ln*8);
      }
      #pragma unroll
      for (int nt=0;nt<3;nt++){
        bh[nt] = *(const short8*)(WrecF + wrecOff(cb,nt,ch,0) + ln*8);
        bl[nt] = *(const short8*)(WrecF + wrecOff(cb,nt,ch,1) + ln*8);
      }
      #pragma unroll
      for (int m=0;m<2;m++)
        #pragma unroll
        for (int nt=0;nt<3;nt++)
          accR[m][nt] = __builtin_amdgcn_mfma_f32_16x16x32_bf16(ah[m], bh[nt], accR[m][nt], 0,0,0);
      #pragma unroll
      for (int m=0;m<2;m++)
        #pragma unroll
        for (int nt=0;nt<3;nt++)
          accR[m][nt] = __builtin_amdgcn_mfma_f32_16x16x32_bf16(ah[m], bl[nt], accR[m][nt], 0,0,0);
      #pragma unroll
      for (int m=0;m<2;m++)
        #pragma unroll
        for (int nt=0;nt<3;nt++)
          accR[m][nt] = __builtin_amdgcn_mfma_f32_16x16x32_bf16(al[m], bh[nt], accR[m][nt], 0,0,0);
    }
  }

  // ---- input projection: 4 chunks of K=32 per k-wave ----
  {
    const int ch0 = kw*4;
    #pragma unroll
    for (int ci=0; ci<4; ci++){
      const int ch = ch0 + ci;
      short8 ah[2], al[2], bh[3], bl[3];
      #pragma unroll
      for (int m=0;m<2;m++){
        const int mt = mw*2+m;
        ah[m] = *(const short8*)(eFt + eOff(mt,ch,0) + ln*8);
        al[m] = *(const short8*)(eFt + eOff(mt,ch,1) + ln*8);
      }
      #pragma unroll
      for (int nt=0;nt<3;nt++){
        bh[nt] = *(const short8*)(WinF + winOff(cb,nt,ch,0) + ln*8);
        bl[nt] = *(const short8*)(WinF + winOff(cb,nt,ch,1) + ln*8);
      }
      #pragma unroll
      for (int m=0;m<2;m++)
        #pragma unroll
        for (int nt=0;nt<3;nt++)
          accI[m][nt] = __builtin_amdgcn_mfma_f32_16x16x32_bf16(ah[m], bh[nt], accI[m][nt], 0,0,0);
      #pragma unroll
      for (int m=0;m<2;m++)
        #pragma unroll
        for (int nt=0;nt<3;nt++)
          accI[m][nt] = __builtin_amdgcn_mfma_f32_16x16x32_bf16(ah[m], bl[nt], accI[m][nt], 0,0,0);
      #pragma unroll
      for (int m=0;m<2;m++)
        #pragma unroll
        for (int nt=0;nt<3;nt++)
          accI[m][nt] = __builtin_amdgcn_mfma_f32_16x16x32_bf16(al[m], bh[nt], accI[m][nt], 0,0,0);
    }
  }

  // ---- k-split reduction + gates (per-lane: lane&15 == u offset) ----
  __shared__ float red[64*48];
  if (kw==1){
    #pragma unroll
    for (int m=0;m<2;m++)
      #pragma unroll
      for (int nt=0;nt<3;nt++)
        #pragma unroll
        for (int reg=0;reg<4;reg++){
          red[ln*48 +      (m*3+nt)*4+reg] = accR[m][nt][reg];
          red[ln*48 + 24 + (m*3+nt)*4+reg] = accI[m][nt][reg];
        }
  }
  __syncthreads();
  if (kw==0){
    const int u = cb*16 + (ln&15);
    const float bz  = b_in[u]       + b_rec[u];
    const float brr = b_in[U_+u]    + b_rec[U_+u];
    const float bxh = b_in[2*U_+u];
    const float brh = b_rec[2*U_+u];
    const int chv = u>>5, jj = u&7, lq = 16*((u>>3)&3);
    #pragma unroll
    for (int m=0;m<2;m++){
      #pragma unroll
      for (int reg=0;reg<4;reg++){
        const int row = (ln>>4)*4 + reg;
        const int b = mw*32 + m*16 + row;
        const float Rz = accR[m][0][reg] + red[ln*48 +      (m*3+0)*4+reg];
        const float Rr = accR[m][1][reg] + red[ln*48 +      (m*3+1)*4+reg];
        const float Rh = accR[m][2][reg] + red[ln*48 +      (m*3+2)*4+reg];
        const float Iz = accI[m][0][reg] + red[ln*48 + 24 + (m*3+0)*4+reg];
        const float Ir = accI[m][1][reg] + red[ln*48 + 24 + (m*3+1)*4+reg];
        const float Ih = accI[m][2][reg] + red[ln*48 + 24 + (m*3+2)*4+reg];

        const float z  = 1.f/(1.f+expf(-(Rz+Iz+bz)));
        const float r  = 1.f/(1.f+expf(-(Rr+Ir+brr)));
        const float hh = tanhf(Ih + bxh + r*(Rh + brh));
        const float hp = hprev[(size_t)b*hstride + u];
        const float hn = z*hp + (1.f-z)*hh;

        out[(size_t)b*((size_t)T_*U_) + (size_t)t*U_ + u] = hn;
        if (t == T_-1) out[(size_t)B_*T_*U_ + (size_t)b*U_ + u] = hn;

        unsigned short hi, lo; split_bf16(hn, hi, lo);
        const int mt = b>>4; const int lnp = (b&15) + lq;
        hFdst[hOff(mt,chv,0) + lnp*8 + jj] = hi;
        hFdst[hOff(mt,chv,1) + lnp*8 + jj] = lo;
      }
    }
  }
}

// ================= Round-0 f32 fallback path =================
__global__ __launch_bounds__(256) void transpose_f32(
    const float* __restrict__ in, float* __restrict__ out, int R, int C)
{
  __shared__ float tile[32][33];
  const int bc = blockIdx.x * 32;
  const int br = blockIdx.y * 32;
  const int tx = threadIdx.x & 31;
  const int ty = threadIdx.x >> 5;
#pragma unroll
  for (int i = 0; i < 32; i += 8)
    tile[ty + i][tx] = in[(size_t)(br + ty + i) * C + (bc + tx)];
  __syncthreads();
#pragma unroll
  for (int i = 0; i < 32; i += 8)
    out[(size_t)(bc + ty + i) * R + (br + tx)] = tile[tx][ty + i];
}

template<bool USE_WT>
__global__ __launch_bounds__(512) void gru_step(
    const float* __restrict__ h_src, int h_stride,
    const int*   __restrict__ x, int t,
    const float* __restrict__ emb,
    const float* __restrict__ Wrec,
    const float* __restrict__ WrecT,
    const float* __restrict__ Win,
    const float* __restrict__ WinT,
    const float* __restrict__ b_in,
    const float* __restrict__ b_rec,
    float* __restrict__ out)
{
  __shared__ float sh[64 * 129];
  const int tid = (int)threadIdx.x;
  const int b   = tid & 63;
  const int j   = tid >> 6;
  const int uj  = j & 3;
  const int kh  = j >> 2;
  const int u   = blockIdx.x * 4 + uj;

  float az = 0.f, ar = 0.f, arh = 0.f, axh = 0.f;

  for (int kc = 0; kc < U_; kc += 128) {
#pragma unroll
    for (int l = tid; l < 2048; l += 512) {
      const int row = l >> 5, c4 = l & 31;
      const int c4r = (c4 + row) & 31;
      const float4 v = *reinterpret_cast<const float4*>(
          h_src + (size_t)row * h_stride + (kc + c4r * 4));
      float* d = &sh[row * 129 + c4r * 4];
      d[0] = v.x; d[1] = v.y; d[2] = v.z; d[3] = v.w;
    }
    __syncthreads();
    const float* hrow = &sh[b * 129 + kh * 64];
    const int kb = kc + kh * 64;
    if (USE_WT) {
      const float4* wz = reinterpret_cast<const float4*>(WrecT + (size_t)u * U_ + kb);
      const float4* wr = reinterpret_cast<const float4*>(WrecT + (size_t)(U_ + u) * U_ + kb);
      const float4* wh = reinterpret_cast<const float4*>(WrecT + (size_t)(2 * U_ + u) * U_ + kb);
#pragma unroll 8
      for (int k4 = 0; k4 < 16; ++k4) {
        const float4 z4 = wz[k4], r4 = wr[k4], h4 = wh[k4];
        const float h0 = hrow[k4*4+0], h1 = hrow[k4*4+1], h2 = hrow[k4*4+2], h3 = hrow[k4*4+3];
        az  += h0*z4.x; az  += h1*z4.y; az  += h2*z4.z; az  += h3*z4.w;
        ar  += h0*r4.x; ar  += h1*r4.y; ar  += h2*r4.z; ar  += h3*r4.w;
        arh += h0*h4.x; arh += h1*h4.y; arh += h2*h4.z; arh += h3*h4.w;
      }
    } else {
#pragma unroll 4
      for (int k = 0; k < 64; ++k) {
        const float hv = hrow[k];
        const size_t roff = (size_t)(kb + k) * U3_;
        az  += hv * Wrec[roff + u];
        ar  += hv * Wrec[roff + U_ + u];
        arh += hv * Wrec[roff + 2 * U_ + u];
      }
    }
    __syncthreads();
  }

  for (int kc = 0; kc < E_; kc += 128) {
#pragma unroll
    for (int l = tid; l < 2048; l += 512) {
      const int row = l >> 5, c4 = l & 31;
      const int c4r = (c4 + row) & 31;
      const int tok = x[row * T_ + t];
      const float4 v = *reinterpret_cast<const float4*>(
          emb + (size_t)tok * E_ + (kc + c4r * 4));
      float* d = &sh[row * 129 + c4r * 4];
      d[0] = v.x; d[1] = v.y; d[2] = v.z; d[3] = v.w;
    }
    __syncthreads();
    const float* erow = &sh[b * 129 + kh * 64];
    const int kb = kc + kh * 64;
    if (USE_WT) {
      const float4* wz = reinterpret_cast<const float4*>(WinT + (size_t)u * E_ + kb);
      const float4* wr = reinterpret_cast<const float4*>(WinT + (size_t)(U_ + u) * E_ + kb);
      const float4* wh = reinterpret_cast<const float4*>(WinT + (size_t)(2 * U_ + u) * E_ + kb);
#pragma unroll 8
      for (int k4 = 0; k4 < 16; ++k4) {
        const float4 z4 = wz[k4], r4 = wr[k4], h4 = wh[k4];
        const float h0 = erow[k4*4+0], h1 = erow[k4*4+1], h2 = erow[k4*4+2], h3 = erow[k4*4+3];
        az  += h0*z4.x; az  += h1*z4.y; az  += h2*z4.z; az  += h3*z4.w;
        ar  += h0*r4.x; ar  += h1*r4.y; ar  += h2*r4.z; ar  += h3*r4.w;
        axh += h0*h4.x; axh += h1*h4.y; axh += h2*h4.z; axh += h3*h4.w;
      }
    } else {
#pragma unroll 4
      for (int k = 0; k < 64; ++k) {
        const float ev = erow[k];
        const size_t roff = (size_t)(kb + k) * U3_;
        az  += ev * Win[roff + u];
        ar  += ev * Win[roff + U_ + u];
        axh += ev * Win[roff + 2 * U_ + u];
      }
    }
    __syncthreads();
  }

  if (kh == 1) {
    sh[(0*4+uj)*64 + b] = az;
    sh[(1*4+uj)*64 + b] = ar;
    sh[(2*4+uj)*64 + b] = arh;
    sh[(3*4+uj)*64 + b] = axh;
  }
  __syncthreads();
  if (kh == 0) {
    az  += sh[(0*4+uj)*64 + b];
    ar  += sh[(1*4+uj)*64 + b];
    arh += sh[(2*4+uj)*64 + b];
    axh += sh[(3*4+uj)*64 + b];

    const float bz  = b_in[u]          + b_rec[u];
    const float brr = b_in[U_ + u]     + b_rec[U_ + u];
    const float bxh = b_in[2 * U_ + u];
    const float brh = b_rec[2 * U_ + u];

    const float z  = 1.f / (1.f + expf(-(az + bz)));
    const float r  = 1.f / (1.f + expf(-(ar + brr)));
    const float hh = tanhf(axh + bxh + r * (arh + brh));
    const float hp = h_src[(size_t)b * h_stride + u];
    const float hn = z * hp + (1.f - z) * hh;

    out[(size_t)b * ((size_t)T_ * U_) + (size_t)t * U_ + u] = hn;
    if (t == T_ - 1)
      out[(size_t)B_ * T_ * U_ + (size_t)b * U_ + u] = hn;
  }
}

extern "C" void kernel_launch(void* const* d_in, const int* in_sizes, int n_in,
                              void* d_out, int out_size, void* d_ws, size_t ws_size,
                              hipStream_t stream) {
  (void)in_sizes; (void)n_in; (void)out_size;
  const int*   x     = (const int*)  d_in[0];
  const float* init  = (const float*)d_in[1];
  const float* emb   = (const float*)d_in[2];
  const float* Win   = (const float*)d_in[3];
  const float* Wrec  = (const float*)d_in[4];
  const float* b_in  = (const float*)d_in[5];
  const float* b_rec = (const float*)d_in[6];
  float* out = (float*)d_out;

  // ---- MFMA path ws layout (ushort units) ----
  const size_t nWrecF = 6291456;    // 64*3*32*2*512
  const size_t nWinF  = 1572864;    // 64*3*8*2*512
  const size_t nhF    = 262144;     // 2 * 131072
  const size_t neF    = 33554432;   // 1024 * 32768
  const size_t needMF = (nWrecF + nWinF + nhF + neF) * sizeof(unsigned short);

  if (d_ws != nullptr && ws_size >= needMF) {
    unsigned short* WrecF = (unsigned short*)d_ws;
    unsigned short* WinF  = WrecF + nWrecF;
    unsigned short* hF    = WinF  + nWinF;
    unsigned short* eF    = hF    + nhF;

    build_wfrag<<<64*3*32, 256, 0, stream>>>(Wrec, WrecF, 32);
    build_wfrag<<<64*3*8,  256, 0, stream>>>(Win,  WinF,  8);
    build_hfrag<<<256, 256, 0, stream>>>(init, hF);      // parity 0
    build_efrag<<<1024, 256, 0, stream>>>(x, emb, eF);

    for (int t = 0; t < T_; ++t) {
      const unsigned short* hs = hF + (size_t)(t & 1) * 131072;
      unsigned short*       hd = hF + (size_t)((t+1) & 1) * 131072;
      const float* hprev = (t == 0) ? init : (out + (size_t)(t-1) * U_);
      const long long hstride = (t == 0) ? (long long)U_ : (long long)T_ * U_;
      gru_step_mfma<<<128, 128, 0, stream>>>(hs, hd, eF + (size_t)t * 32768,
          WrecF, WinF, hprev, hstride, b_in, b_rec, out, t);
    }
    return;
  }

  // ---- fallback: Round-0 f32 path ----
  float* WrecT = (float*)d_ws;
  float* WinT  = WrecT + (size_t)U3_ * U_;
  const size_t needT = ((size_t)U3_ * U_ + (size_t)U3_ * E_) * sizeof(float);
  const bool useWT = (d_ws != nullptr) && (ws_size >= needT);

  if (useWT) {
    transpose_f32<<<dim3(U3_/32, U_/32), 256, 0, stream>>>(Wrec, WrecT, U_, U3_);
    transpose_f32<<<dim3(U3_/32, E_/32), 256, 0, stream>>>(Win,  WinT,  E_, U3_);
    for (int t = 0; t < T_; ++t) {
      const float* hsrc = (t == 0) ? init : (out + (size_t)(t-1) * U_);
      const int hs = (t == 0) ? U_ : T_ * U_;
      gru_step<true><<<256, 512, 0, stream>>>(hsrc, hs, x, t, emb,
          Wrec, WrecT, Win, WinT, b_in, b_rec, out);
    }
  } else {
    for (int t = 0; t < T_; ++t) {
      const float* hsrc = (t == 0) ? init : (out + (size_t)(t-1) * U_);
      const int hs = (t == 0) ? U_ : T_ * U_;
      gru_step<false><<<256, 512, 0, stream>>>(hsrc, hs, x, t, emb,
          Wrec, WrecT, Win, WinT, b_in, b_rec, out);
    }
  }
}